// Round 23
// baseline (276.518 us; speedup 1.0000x reference)
//
#include <hip/hip_runtime.h>
#include <hip/hip_bf16.h>
#include <math.h>

#define BB 512
#define CC 50

typedef __attribute__((ext_vector_type(8))) __bf16 bf16x8;
typedef __attribute__((ext_vector_type(4))) float f32x4;

// ---------------- zero-fill out[0 : 512*692*10) ----------------
__global__ void k_zero(float* __restrict__ out, int n4) {
  int i = blockIdx.x * 256 + threadIdx.x;
  if (i < n4) {
    float4 z = {0.f, 0.f, 0.f, 0.f};
    ((float4*)out)[i] = z;
  }
}

// ---------------- pack head weights ----------------
// W1p[512 j][64 k] bf16: k<50 = l1w[j][k], k==50 = l1b[j], else 0; j>=500 all 0.
// W2t[512 j][12] f32:  n<10 && j<500 = l2w[n][j], else 0.
__global__ void k_pack(const float* __restrict__ l1w, const float* __restrict__ l1b,
                       const float* __restrict__ l2w,
                       __bf16* __restrict__ W1p, float* __restrict__ W2t) {
  int idx = blockIdx.x * 256 + threadIdx.x;
  if (idx < 512 * 64) {
    int j = idx >> 6, k = idx & 63;
    float v = 0.f;
    if (j < 500) {
      if (k < 50) v = l1w[j * 50 + k];
      else if (k == 50) v = l1b[j];
    }
    W1p[idx] = (__bf16)v;
  } else if (idx < 512 * 64 + 512 * 12) {
    int i2 = idx - 512 * 64;
    int j = i2 / 12, n = i2 % 12;
    W2t[i2] = (n < 10 && j < 500) ? l2w[n * 500 + j] : 0.f;
  }
}

// ---------------- conv1 (1->50, 3x3) + relu + pool2 -> h1[512,50,13,13] ----------------
__global__ void k_conv1(const float* __restrict__ x, const float* __restrict__ w,
                        const float* __restrict__ bias, float* __restrict__ h1) {
  int idx = blockIdx.x * 256 + threadIdx.x;
  if (idx >= BB * CC * 169) return;
  int b = idx / (CC * 169);
  int rem = idx % (CC * 169);
  int c = rem / 169;
  int p = rem % 169;
  int py = p / 13, px = p % 13;
  const float* xi = x + b * 784;
  float wr[9];
#pragma unroll
  for (int i = 0; i < 9; i++) wr[i] = w[c * 9 + i];
  float m = -INFINITY;
#pragma unroll
  for (int dy = 0; dy < 2; dy++)
#pragma unroll
    for (int dx = 0; dx < 2; dx++) {
      int y0 = 2 * py + dy, x0 = 2 * px + dx;
      float s = 0.f;
#pragma unroll
      for (int ky = 0; ky < 3; ky++)
#pragma unroll
        for (int kx = 0; kx < 3; kx++)
          s += xi[(y0 + ky) * 28 + x0 + kx] * wr[ky * 3 + kx];
      m = fmaxf(m, s);
    }
  h1[idx] = fmaxf(m + bias[c], 0.f);
}

// ---------------- router 1 (argmax of 3) + pool7, fused ----------------
__global__ void k_d1p7(const float* __restrict__ h1, const float* __restrict__ w,
                       const float* __restrict__ bias, int* __restrict__ d1i,
                       float* __restrict__ outd1, float* __restrict__ p7) {
  int b = blockIdx.x, t = threadIdx.x;
  const float* hb = h1 + b * 8450;
  float s0 = 0.f, s1 = 0.f, s2 = 0.f;
  for (int i = t; i < 8450; i += 256) {
    float v = hb[i];
    s0 += v * w[i];
    s1 += v * w[8450 + i];
    s2 += v * w[16900 + i];
  }
#pragma unroll
  for (int off = 32; off >= 1; off >>= 1) {
    s0 += __shfl_down(s0, off);
    s1 += __shfl_down(s1, off);
    s2 += __shfl_down(s2, off);
  }
  __shared__ float red[4][3];
  if ((t & 63) == 0) { red[t >> 6][0] = s0; red[t >> 6][1] = s1; red[t >> 6][2] = s2; }
  __syncthreads();
  if (t == 0) {
    float l0 = bias[0], l1v = bias[1], l2v = bias[2];
    for (int wv = 0; wv < 4; wv++) { l0 += red[wv][0]; l1v += red[wv][1]; l2v += red[wv][2]; }
    int idx = 0; float best = l0;
    if (l1v > best) { best = l1v; idx = 1; }
    if (l2v > best) { best = l2v; idx = 2; }
    d1i[b] = idx;
    outd1[b] = (float)idx;
  }
  if (t < 50) {
    const float* hp = hb + t * 169;
    float m = -INFINITY;
#pragma unroll
    for (int y = 0; y < 7; y++)
#pragma unroll
      for (int x = 0; x < 7; x++) m = fmaxf(m, hp[y * 13 + x]);
    p7[b * 50 + t] = m;
  }
}

// ---------------- merged conv2/conv3 (13x13 -> 11x11) + relu + pool2 -> [50,5,5] ----------------
// grid = 1024: mode = id&1 (0: conv2 -> h2, all samples; 1: conv3 on c33(h1), d1==1 -> c3d).
// ic processed in TWO 25-plane chunks through a single 26KB LDS buffer.
// v2: each compute thread (t<125) owns TWO output channels (oc, oc+1) and reuses the
// row reads r[4][13] for both -> LDS instructions per FMA halve (the diagnosed bound).
// Per-oc accumulation order (ic ascending, same tap order) bitwise-identical to R20/R22.
__global__ __launch_bounds__(256) void k_conv5m(
    const float* __restrict__ h1,
    const float* __restrict__ c2w, const float* __restrict__ c2b,
    const float* __restrict__ c3w, const float* __restrict__ c3b,
    const int* __restrict__ d1i,
    const float* __restrict__ w13, const float* __restrict__ b13,
    float* __restrict__ h2, float* __restrict__ c3d) {
  int id = blockIdx.x;
  int mode = id & 1, b = id >> 1;
  if (mode == 1 && d1i[b] != 1) return;   // uniform block exit before any barrier
  __shared__ float sh[25 * 260];          // one 25-plane chunk, row stride 20
  __shared__ float w13s[182];
  int t = threadIdx.x;
  int oc0 = (t / 5) * 2, py = t % 5;      // valid when t < 125: ocs {oc0, oc0+1}
  const float* wall = mode ? c3w : c2w;
  float acc[2][5][4];
#pragma unroll
  for (int u = 0; u < 2; u++)
#pragma unroll
    for (int i = 0; i < 5; i++)
#pragma unroll
      for (int j = 0; j < 4; j++) acc[u][i][j] = 0.f;

  for (int half = 0; half < 2; ++half) {
    if (half > 0) __syncthreads();        // prior chunk's compute done
    // stage 25 planes (ic = half*25 .. +24): 25*169 = 4225 source elements
    for (int i = t; i < 4225; i += 256) {
      int ic = i / 169, r = i % 169;
      sh[ic * 260 + (r / 13) * 20 + (r % 13)] = h1[b * 8450 + (half * 25 + ic) * 169 + r];
    }
    if (half == 0 && mode == 1) {
      for (int i = t; i < 182; i += 256) w13s[i] = (i < 169) ? w13[i] : b13[i - 169];
    }
    __syncthreads();
    if (mode == 1) {
      // c33 on this chunk: row'[x] = sum_k row[k]*W13[x][k] + b13[x], per (ic,row)
      for (int p = t; p < 325; p += 256) {
        float* row = sh + (p / 13) * 260 + (p % 13) * 20;
        float r[13];
#pragma unroll
        for (int k = 0; k < 13; k++) r[k] = row[k];
#pragma unroll
        for (int xx = 0; xx < 13; xx++) {
          float s = w13s[169 + xx];
#pragma unroll
          for (int k = 0; k < 13; k++) s += r[k] * w13s[xx * 13 + k];
          row[xx] = s;
        }
      }
      __syncthreads();
    }
    if (t < 125) {
      for (int icl = 0; icl < 25; ++icl) {
        int icg = half * 25 + icl;
        // both ocs' weights issued up front (independent loads, overlap with row reads)
        float wv0[9], wv1[9];
#pragma unroll
        for (int i = 0; i < 9; i++) wv0[i] = wall[oc0 * 450 + icg * 9 + i];
#pragma unroll
        for (int i = 0; i < 9; i++) wv1[i] = wall[(oc0 + 1) * 450 + icg * 9 + i];
        // rows read ONCE, reused for both ocs
        float r[4][13];
        const float* rp = sh + icl * 260 + 2 * py * 20;
#pragma unroll
        for (int rr = 0; rr < 4; rr++) {
          const float* p4 = rp + rr * 20;
          float4 q0 = *(const float4*)(p4);
          float4 q1 = *(const float4*)(p4 + 4);
          float4 q2 = *(const float4*)(p4 + 8);
          r[rr][0] = q0.x; r[rr][1] = q0.y; r[rr][2] = q0.z; r[rr][3] = q0.w;
          r[rr][4] = q1.x; r[rr][5] = q1.y; r[rr][6] = q1.z; r[rr][7] = q1.w;
          r[rr][8] = q2.x; r[rr][9] = q2.y; r[rr][10] = q2.z; r[rr][11] = q2.w;
          r[rr][12] = p4[12];
        }
#pragma unroll
        for (int u = 0; u < 2; ++u) {
          const float* wvu = u ? wv1 : wv0;
#pragma unroll
          for (int px = 0; px < 5; px++)
#pragma unroll
            for (int dy = 0; dy < 2; dy++)
#pragma unroll
              for (int dx = 0; dx < 2; dx++) {
                float s = acc[u][px][dy * 2 + dx];
                int x0 = 2 * px + dx;
#pragma unroll
                for (int ky = 0; ky < 3; ky++)
#pragma unroll
                  for (int kx = 0; kx < 3; kx++)
                    s += r[dy + ky][x0 + kx] * wvu[ky * 3 + kx];
                acc[u][px][dy * 2 + dx] = s;
              }
        }
      }
    }
  }
  if (t >= 125) return;
  float* outp = mode ? c3d : h2;
  const float* bp = mode ? c3b : c2b;
#pragma unroll
  for (int u = 0; u < 2; ++u) {
    float bs = bp[oc0 + u];
#pragma unroll
    for (int px = 0; px < 5; px++) {
      float m = fmaxf(fmaxf(acc[u][px][0], acc[u][px][1]),
                      fmaxf(acc[u][px][2], acc[u][px][3]));
      outp[(b * 50 + oc0 + u) * 25 + py * 5 + px] = fmaxf(m + bs, 0.f);
    }
  }
}

// ---------------- fused: router 2 + c32 (d2==0) + l12 (d2==1), h2 staged once ----------------
__global__ __launch_bounds__(256) void k_d2c(const float* __restrict__ h2,
                                             const float* __restrict__ d2w,
                                             const float* __restrict__ d2b,
                                             const float* __restrict__ c3w,
                                             const float* __restrict__ c3b,
                                             const float* __restrict__ c2l1w,
                                             const float* __restrict__ c2l1b,
                                             const int* __restrict__ d1i,
                                             int* __restrict__ d2i,
                                             float* __restrict__ outd2,
                                             float* __restrict__ c32,
                                             float* __restrict__ l12) {
  int b = blockIdx.x, t = threadIdx.x;
  __shared__ float hs[1250];
  __shared__ float wls[2500];
  __shared__ float bls[500];
  __shared__ float red[4][2];
  __shared__ int sd2;
  for (int i = t; i < 1250; i += 256) hs[i] = h2[b * 1250 + i];
  __syncthreads();
  float s0 = 0.f, s1 = 0.f;
  for (int i = t; i < 1250; i += 256) {
    float v = hs[i];
    s0 += v * d2w[i];
    s1 += v * d2w[1250 + i];
  }
#pragma unroll
  for (int off = 32; off >= 1; off >>= 1) {
    s0 += __shfl_down(s0, off);
    s1 += __shfl_down(s1, off);
  }
  if ((t & 63) == 0) { red[t >> 6][0] = s0; red[t >> 6][1] = s1; }
  __syncthreads();
  if (t == 0) {
    float l0 = d2b[0] + red[0][0] + red[1][0] + red[2][0] + red[3][0];
    float l1v = d2b[1] + red[0][1] + red[1][1] + red[2][1] + red[3][1];
    int idx = (l1v > l0) ? 1 : 0;
    d2i[b] = idx;
    outd2[b] = (float)idx;
    sd2 = idx;
  }
  __syncthreads();
  int d2v = sd2;
  if (d1i[b] != 0) return;
  if (d2v == 0) {
    if (t < 50) {
      const float* wb = c3w + t * 450;
      float a[4] = {0.f, 0.f, 0.f, 0.f};
      for (int ic = 0; ic < 50; ic++) {
        float r[4][4];
#pragma unroll
        for (int y = 0; y < 4; y++)
#pragma unroll
          for (int xx = 0; xx < 4; xx++) r[y][xx] = hs[ic * 25 + y * 5 + xx];
        float wv[9];
#pragma unroll
        for (int i = 0; i < 9; i++) wv[i] = wb[ic * 9 + i];
#pragma unroll
        for (int py = 0; py < 2; py++)
#pragma unroll
          for (int px = 0; px < 2; px++) {
            float s = a[py * 2 + px];
#pragma unroll
            for (int ky = 0; ky < 3; ky++)
#pragma unroll
              for (int kx = 0; kx < 3; kx++)
                s += r[py + ky][px + kx] * wv[ky * 3 + kx];
            a[py * 2 + px] = s;
          }
      }
      float m = fmaxf(fmaxf(a[0], a[1]), fmaxf(a[2], a[3]));
      c32[b * 50 + t] = fmaxf(m + c3b[t], 0.f);
    }
  } else {
    for (int i = t; i < 2500; i += 256) wls[i] = c2l1w[i];
    for (int i = t; i < 500; i += 256) bls[i] = c2l1b[i];
    __syncthreads();
    for (int o = t; o < 8300; o += 256) {
      int c = o / 166, tt = o % 166;
      const float* hb = hs + c * 25;
      float m = -INFINITY;
#pragma unroll
      for (int i = 0; i < 3; i++) {
        float a0 = hb[i * 5 + 0], a1 = hb[i * 5 + 1], a2 = hb[i * 5 + 2],
              a3 = hb[i * 5 + 3], a4 = hb[i * 5 + 4];
#pragma unroll
        for (int dj = 0; dj < 3; dj++) {
          int j = 3 * tt + dj;
          const float* wj = wls + j * 5;
          float s = bls[j] + a0 * wj[0] + a1 * wj[1] + a2 * wj[2] + a3 * wj[3] + a4 * wj[4];
          m = fmaxf(m, s);
        }
      }
      l12[b * 8300 + o] = m;
    }
  }
}

// ---------------- count active head rows per sample + prefix sum ----------------
__global__ void k_count(const int* __restrict__ d1i, const int* __restrict__ d2i,
                        int* __restrict__ off, int* __restrict__ ntot) {
  __shared__ int s[512];
  int t = threadIdx.x;
  int d1 = d1i[t], d2 = d2i[t];
  int nr = (d1 == 2) ? 500 : (d1 == 1) ? 25 : (d2 == 1) ? 166 : 1;
  s[t] = nr;
  __syncthreads();
  for (int o = 1; o < 512; o <<= 1) {
    int v = (t >= o) ? s[t - o] : 0;
    __syncthreads();
    s[t] += v;
    __syncthreads();
  }
  off[t] = s[t] - nr;
  if (t == 511) ntot[0] = s[511];
}

// ---------------- fill compacted row table: rowtab[i] = (b<<10) | out-row ----------------
__global__ void k_fill(const int* __restrict__ d1i, const int* __restrict__ d2i,
                       const int* __restrict__ off, int* __restrict__ rowtab) {
  int b = blockIdx.x;
  int d1 = d1i[b], d2 = d2i[b];
  int nr, rstart;
  if (d1 == 2)      { nr = 500; rstart = 0; }
  else if (d1 == 1) { nr = 25;  rstart = 667; }
  else if (d2 == 1) { nr = 166; rstart = 500; }
  else              { nr = 1;   rstart = 666; }
  int o = off[b];
  for (int i = threadIdx.x; i < nr; i += 256)
    rowtab[o + i] = (b << 10) | (rstart + i);
}

// XOR swizzle for the W1 LDS chunk (16KB): both write and read sides.
__device__ __forceinline__ int swz(int byteoff) {
  return byteoff ^ (((byteoff >> 7) & 7) << 4);
}

// ---------------- head GEMM, compacted (v8): zero global loads in the main loop ----------------
__global__ __launch_bounds__(256, 3) void k_headc(
    const float* __restrict__ c3d, const float* __restrict__ c32,
    const float* __restrict__ p7, const float* __restrict__ l12buf,
    const int* __restrict__ rowtab, const int* __restrict__ ntotp,
    const __bf16* __restrict__ W1p, const float* __restrict__ W2t,
    const float* __restrict__ l2b,
    const float* __restrict__ c1l1w, const float* __restrict__ c1l1b,
    float* __restrict__ out) {
  int ntot = ntotp[0];
  int blkbase = blockIdx.x * 64;
  if (blkbase >= ntot) return;          // uniform whole-block exit (before any barrier)

  __shared__ __align__(16) char wlds[16384];    // W1 phase buffer (8 j-tiles)
  __shared__ __align__(16) float w2s[512 * 12]; // W2, staged once (24KB)
  int t = threadIdx.x;
  int wv = t >> 6, lane = t & 63;
  int lr = lane & 15, lg = lane >> 4;

  // stage W2 once (1536 float4s / 256 threads = 6 each, coalesced)
  for (int i = t; i < 1536; i += 256)
    ((float4*)w2s)[i] = ((const float4*)W2t)[i];

  // ---- gather this lane's A-frag row (A layout: row = lr)
  int row = blkbase + wv * 16 + lr;
  int rowc = (row < ntot) ? row : (ntot - 1);
  int e = rowtab[rowc];
  int gb = e >> 10, orow = e & 1023;
  bf16x8 a1[2];
  {
    float pv = 0.f;
    const float* wsrc = nullptr;
    const float* bsrc = nullptr;
    const float* src = nullptr;
    bool isl11 = (orow < 500);
    if (isl11) {
      pv = p7[gb * 50 + orow / 10];
      int q = (orow % 10) * 50;
      wsrc = c1l1w + q;
      bsrc = c1l1b + q;
    } else if (orow < 666) {
      src = l12buf + gb * 8300 + (orow - 500) * 50;
    } else if (orow == 666) {
      src = c32 + gb * 50;
    } else {
      src = c3d + gb * 1250 + (orow - 667) * 50;
    }
#pragma unroll
    for (int ks = 0; ks < 2; ++ks) {
      float v[8];
      int k0 = ks * 32 + lg * 8;
      if (ks == 0 || lg < 2) {
        if (isl11) {
#pragma unroll
          for (int i = 0; i < 8; i += 2) {
            float2 wq = *(const float2*)(wsrc + k0 + i);
            float2 bq = *(const float2*)(bsrc + k0 + i);
            v[i] = pv * wq.x + bq.x;
            v[i + 1] = pv * wq.y + bq.y;
          }
        } else {
#pragma unroll
          for (int i = 0; i < 8; i += 2) {
            float2 q = *(const float2*)(src + k0 + i);
            v[i] = q.x; v[i + 1] = q.y;
          }
        }
      } else if (lg == 2) {
        float2 q;
        if (isl11) {
          float2 wq = *(const float2*)(wsrc + 48);
          float2 bq = *(const float2*)(bsrc + 48);
          q.x = pv * wq.x + bq.x; q.y = pv * wq.y + bq.y;
        } else {
          q = *(const float2*)(src + 48);
        }
        v[0] = q.x; v[1] = q.y; v[2] = 1.0f;
        v[3] = 0.f; v[4] = 0.f; v[5] = 0.f; v[6] = 0.f; v[7] = 0.f;
      } else {
#pragma unroll
        for (int i = 0; i < 8; ++i) v[i] = 0.f;
      }
      bf16x8 a;
#pragma unroll
      for (int i = 0; i < 8; ++i) a[i] = (__bf16)v[i];
      a1[ks] = a;
    }
  }

  float acc[4][10];
#pragma unroll
  for (int r = 0; r < 4; ++r)
#pragma unroll
    for (int n = 0; n < 10; ++n) acc[r][n] = 0.f;

  for (int p = 0; p < 4; ++p) {
    if (p > 0) __syncthreads();         // all waves done reading phase p-1
    // stage 16KB of W1 (j-tiles p*8 .. p*8+7), swizzled (64B/thread)
    {
      const char* src = (const char*)W1p + p * 16384 + t * 64;
#pragma unroll
      for (int i = 0; i < 4; ++i) {
        float4 q = *(const float4*)(src + i * 16);
        *(float4*)(wlds + swz(t * 64 + i * 16)) = q;
      }
    }
    __syncthreads();
#pragma unroll
    for (int jl = 0; jl < 8; ++jl) {
      int jt = p * 8 + jl;
      int boff = jl * 2048 + lr * 128 + lg * 16;
      bf16x8 b0 = *(const bf16x8*)(wlds + swz(boff));
      bf16x8 b1 = *(const bf16x8*)(wlds + swz(boff + 64));
      const float* wr = w2s + (jt * 16 + lr) * 12;
      float4 w20 = *(const float4*)(wr);
      float4 w21 = *(const float4*)(wr + 4);
      float2 w22 = *(const float2*)(wr + 8);
      f32x4 h = {0.f, 0.f, 0.f, 0.f};
      h = __builtin_amdgcn_mfma_f32_16x16x32_bf16(a1[0], b0, h, 0, 0, 0);
      h = __builtin_amdgcn_mfma_f32_16x16x32_bf16(a1[1], b1, h, 0, 0, 0);
      float w2v[10] = {w20.x, w20.y, w20.z, w20.w, w21.x, w21.y, w21.z, w21.w, w22.x, w22.y};
#pragma unroll
      for (int r = 0; r < 4; ++r) {
        float hv = fmaxf(h[r], 0.f);
#pragma unroll
        for (int n = 0; n < 10; ++n) acc[r][n] += hv * w2v[n];
      }
    }
  }

  // ---- reduce over 16 lr lanes (j-partition)
#pragma unroll
  for (int r = 0; r < 4; ++r)
#pragma unroll
    for (int n = 0; n < 10; ++n) {
      float v = acc[r][n];
      v += __shfl_xor(v, 1);
      v += __shfl_xor(v, 2);
      v += __shfl_xor(v, 4);
      v += __shfl_xor(v, 8);
      acc[r][n] = v;
    }
  // ---- in-lane log-softmax + write (lane lr==0 holds rows m = lg*4 + r)
  if (lr == 0) {
#pragma unroll
    for (int r = 0; r < 4; ++r) {
      int rw = blkbase + wv * 16 + lg * 4 + r;
      if (rw < ntot) {
        int e2 = rowtab[rw];
        int b2 = e2 >> 10, orow2 = e2 & 1023;
        float o[10];
        float m = -INFINITY;
#pragma unroll
        for (int n = 0; n < 10; ++n) {
          o[n] = acc[r][n] + l2b[n];
          m = fmaxf(m, o[n]);
        }
        float s = 0.f;
#pragma unroll
        for (int n = 0; n < 10; ++n) s += expf(o[n] - m);
        float lse = m + logf(s);
        float* orowp = out + (b2 * 692 + orow2) * 10;
#pragma unroll
        for (int n = 0; n < 10; ++n) orowp[n] = o[n] - lse;
      }
    }
  }
}

extern "C" void kernel_launch(void* const* d_in, const int* in_sizes, int n_in,
                              void* d_out, int out_size, void* d_ws, size_t ws_size,
                              hipStream_t stream) {
  const float* x     = (const float*)d_in[0];
  const float* c1w   = (const float*)d_in[1];
  const float* c1b   = (const float*)d_in[2];
  const float* c2w   = (const float*)d_in[3];
  const float* c2b   = (const float*)d_in[4];
  const float* c3w   = (const float*)d_in[5];
  const float* c3b   = (const float*)d_in[6];
  const float* l1w   = (const float*)d_in[7];
  const float* l1b   = (const float*)d_in[8];
  const float* l2w   = (const float*)d_in[9];
  const float* l2b   = (const float*)d_in[10];
  const float* d1w   = (const float*)d_in[11];
  const float* d1b   = (const float*)d_in[12];
  const float* d2w   = (const float*)d_in[13];
  const float* d2b   = (const float*)d_in[14];
  const float* c13w  = (const float*)d_in[15];
  const float* c13b  = (const float*)d_in[16];
  const float* c1l1w = (const float*)d_in[17];
  const float* c1l1b = (const float*)d_in[18];
  const float* c2l1w = (const float*)d_in[19];
  const float* c2l1b = (const float*)d_in[20];
  float* out = (float*)d_out;

  float* ws  = (float*)d_ws;
  float* h1  = ws;                 // 4,326,400 floats
  float* h2  = h1 + 4326400;       // 640,000
  float* c3d = h2 + 640000;        // 640,000
  float* c32 = c3d + 640000;       // 25,600
  float* p7  = c32 + 25600;        // 25,600
  int*   d1i = (int*)(p7 + 25600); // 512
  int*   d2i = d1i + 512;          // 512
  __bf16* W1p = (__bf16*)(d2i + 512);    // 512*64 bf16 = 16384 floats
  float* W2t = (float*)(W1p + 512 * 64); // 6144 floats
  int* off    = (int*)(W2t + 512 * 12);  // 512
  int* ntot   = off + 512;               // 4 (padded)
  int* rowtab = ntot + 4;                // 262,144
  // l12buf aliases h1: written by k_d2c AFTER the last h1 reader (k_conv5m).
  float* l12buf = h1;

  float* outd1 = out + 512 * 692 * 10;
  float* outd2 = outd1 + 512;

  k_zero<<<3460, 256, 0, stream>>>(out, 885510);
  k_pack<<<153, 256, 0, stream>>>(l1w, l1b, l2w, W1p, W2t);
  k_conv1<<<16900, 256, 0, stream>>>(x, c1w, c1b, h1);
  k_d1p7<<<512, 256, 0, stream>>>(h1, d1w, d1b, d1i, outd1, p7);
  k_conv5m<<<1024, 256, 0, stream>>>(h1, c2w, c2b, c3w, c3b, d1i,
                                     c13w, c13b, h2, c3d);
  k_d2c<<<512, 256, 0, stream>>>(h2, d2w, d2b, c3w, c3b, c2l1w, c2l1b,
                                 d1i, d2i, outd2, c32, l12buf);
  k_count<<<1, 512, 0, stream>>>(d1i, d2i, off, ntot);
  k_fill<<<512, 256, 0, stream>>>(d1i, d2i, off, rowtab);
  k_headc<<<4000, 256, 0, stream>>>(c3d, c32, p7, l12buf, rowtab, ntot,
                                    W1p, W2t, l2b, c1l1w, c1l1b, out);
}

// Round 24
// 206.839 us; speedup vs baseline: 1.3369x; 1.3369x over previous
//
#include <hip/hip_runtime.h>
#include <hip/hip_bf16.h>
#include <math.h>

#define BB 512
#define CC 50

typedef __attribute__((ext_vector_type(8))) __bf16 bf16x8;
typedef __attribute__((ext_vector_type(4))) float f32x4;

// ---------------- zero-fill out[0 : 512*692*10) ----------------
__global__ void k_zero(float* __restrict__ out, int n4) {
  int i = blockIdx.x * 256 + threadIdx.x;
  if (i < n4) {
    float4 z = {0.f, 0.f, 0.f, 0.f};
    ((float4*)out)[i] = z;
  }
}

// ---------------- pack head weights ----------------
// W1p[512 j][64 k] bf16: k<50 = l1w[j][k], k==50 = l1b[j], else 0; j>=500 all 0.
// W2t[512 j][12] f32:  n<10 && j<500 = l2w[n][j], else 0.
__global__ void k_pack(const float* __restrict__ l1w, const float* __restrict__ l1b,
                       const float* __restrict__ l2w,
                       __bf16* __restrict__ W1p, float* __restrict__ W2t) {
  int idx = blockIdx.x * 256 + threadIdx.x;
  if (idx < 512 * 64) {
    int j = idx >> 6, k = idx & 63;
    float v = 0.f;
    if (j < 500) {
      if (k < 50) v = l1w[j * 50 + k];
      else if (k == 50) v = l1b[j];
    }
    W1p[idx] = (__bf16)v;
  } else if (idx < 512 * 64 + 512 * 12) {
    int i2 = idx - 512 * 64;
    int j = i2 / 12, n = i2 % 12;
    W2t[i2] = (n < 10 && j < 500) ? l2w[n * 500 + j] : 0.f;
  }
}

// ---------------- conv1 (1->50, 3x3) + relu + pool2 -> h1[512,50,13,13] ----------------
__global__ void k_conv1(const float* __restrict__ x, const float* __restrict__ w,
                        const float* __restrict__ bias, float* __restrict__ h1) {
  int idx = blockIdx.x * 256 + threadIdx.x;
  if (idx >= BB * CC * 169) return;
  int b = idx / (CC * 169);
  int rem = idx % (CC * 169);
  int c = rem / 169;
  int p = rem % 169;
  int py = p / 13, px = p % 13;
  const float* xi = x + b * 784;
  float wr[9];
#pragma unroll
  for (int i = 0; i < 9; i++) wr[i] = w[c * 9 + i];
  float m = -INFINITY;
#pragma unroll
  for (int dy = 0; dy < 2; dy++)
#pragma unroll
    for (int dx = 0; dx < 2; dx++) {
      int y0 = 2 * py + dy, x0 = 2 * px + dx;
      float s = 0.f;
#pragma unroll
      for (int ky = 0; ky < 3; ky++)
#pragma unroll
        for (int kx = 0; kx < 3; kx++)
          s += xi[(y0 + ky) * 28 + x0 + kx] * wr[ky * 3 + kx];
      m = fmaxf(m, s);
    }
  h1[idx] = fmaxf(m + bias[c], 0.f);
}

// ---------------- router 1 (argmax of 3) + pool7, fused ----------------
__global__ void k_d1p7(const float* __restrict__ h1, const float* __restrict__ w,
                       const float* __restrict__ bias, int* __restrict__ d1i,
                       float* __restrict__ outd1, float* __restrict__ p7) {
  int b = blockIdx.x, t = threadIdx.x;
  const float* hb = h1 + b * 8450;
  float s0 = 0.f, s1 = 0.f, s2 = 0.f;
  for (int i = t; i < 8450; i += 256) {
    float v = hb[i];
    s0 += v * w[i];
    s1 += v * w[8450 + i];
    s2 += v * w[16900 + i];
  }
#pragma unroll
  for (int off = 32; off >= 1; off >>= 1) {
    s0 += __shfl_down(s0, off);
    s1 += __shfl_down(s1, off);
    s2 += __shfl_down(s2, off);
  }
  __shared__ float red[4][3];
  if ((t & 63) == 0) { red[t >> 6][0] = s0; red[t >> 6][1] = s1; red[t >> 6][2] = s2; }
  __syncthreads();
  if (t == 0) {
    float l0 = bias[0], l1v = bias[1], l2v = bias[2];
    for (int wv = 0; wv < 4; wv++) { l0 += red[wv][0]; l1v += red[wv][1]; l2v += red[wv][2]; }
    int idx = 0; float best = l0;
    if (l1v > best) { best = l1v; idx = 1; }
    if (l2v > best) { best = l2v; idx = 2; }
    d1i[b] = idx;
    outd1[b] = (float)idx;
  }
  if (t < 50) {
    const float* hp = hb + t * 169;
    float m = -INFINITY;
#pragma unroll
    for (int y = 0; y < 7; y++)
#pragma unroll
      for (int x = 0; x < 7; x++) m = fmaxf(m, hp[y * 13 + x]);
    p7[b * 50 + t] = m;
  }
}

// ---------------- merged conv2/conv3 (13x13 -> 11x11) + relu + pool2 -> [50,5,5] ----------------
// grid = 1024: mode = id&1 (0: conv2 -> h2, all samples; 1: conv3 on c33(h1), d1==1 -> c3d).
// ic processed in TWO 25-plane chunks through a single 26KB LDS buffer.
// R20/R22 configuration (best measured): 256 threads, no min-waves hint (VGPR 128, no spill).
__global__ __launch_bounds__(256) void k_conv5m(
    const float* __restrict__ h1,
    const float* __restrict__ c2w, const float* __restrict__ c2b,
    const float* __restrict__ c3w, const float* __restrict__ c3b,
    const int* __restrict__ d1i,
    const float* __restrict__ w13, const float* __restrict__ b13,
    float* __restrict__ h2, float* __restrict__ c3d) {
  int id = blockIdx.x;
  int mode = id & 1, b = id >> 1;
  if (mode == 1 && d1i[b] != 1) return;   // uniform block exit before any barrier
  __shared__ float sh[25 * 260];          // one 25-plane chunk, row stride 20
  __shared__ float w13s[182];
  int t = threadIdx.x;
  int oc = t / 5, py = t % 5;             // valid when t < 250
  const float* wb = (mode ? c3w : c2w) + oc * 450;
  float acc[5][4];
#pragma unroll
  for (int i = 0; i < 5; i++)
#pragma unroll
    for (int j = 0; j < 4; j++) acc[i][j] = 0.f;

  for (int half = 0; half < 2; ++half) {
    if (half > 0) __syncthreads();        // prior chunk's compute done
    // stage 25 planes (ic = half*25 .. +24): 25*169 = 4225 source elements
    for (int i = t; i < 4225; i += 256) {
      int ic = i / 169, r = i % 169;
      sh[ic * 260 + (r / 13) * 20 + (r % 13)] = h1[b * 8450 + (half * 25 + ic) * 169 + r];
    }
    if (half == 0 && mode == 1) {
      for (int i = t; i < 182; i += 256) w13s[i] = (i < 169) ? w13[i] : b13[i - 169];
    }
    __syncthreads();
    if (mode == 1) {
      // c33 on this chunk: row'[x] = sum_k row[k]*W13[x][k] + b13[x], per (ic,row)
      for (int p = t; p < 325; p += 256) {
        float* row = sh + (p / 13) * 260 + (p % 13) * 20;
        float r[13];
#pragma unroll
        for (int k = 0; k < 13; k++) r[k] = row[k];
#pragma unroll
        for (int xx = 0; xx < 13; xx++) {
          float s = w13s[169 + xx];
#pragma unroll
          for (int k = 0; k < 13; k++) s += r[k] * w13s[xx * 13 + k];
          row[xx] = s;
        }
      }
      __syncthreads();
    }
    if (t < 250) {
      // 25 ic in this chunk: 12 pairs + 1 single, pair-top weight batching
      for (int icl = 0; icl < 24; icl += 2) {
        int icg = half * 25 + icl;
        float wv0[9], wv1[9];
#pragma unroll
        for (int i = 0; i < 9; i++) wv0[i] = wb[icg * 9 + i];
#pragma unroll
        for (int i = 0; i < 9; i++) wv1[i] = wb[icg * 9 + 9 + i];
#pragma unroll
        for (int u = 0; u < 2; ++u) {
          const float* wvu = u ? wv1 : wv0;
          float r[4][13];
          const float* rp = sh + (icl + u) * 260 + 2 * py * 20;
#pragma unroll
          for (int rr = 0; rr < 4; rr++) {
            const float* p4 = rp + rr * 20;
            float4 q0 = *(const float4*)(p4);
            float4 q1 = *(const float4*)(p4 + 4);
            float4 q2 = *(const float4*)(p4 + 8);
            r[rr][0] = q0.x; r[rr][1] = q0.y; r[rr][2] = q0.z; r[rr][3] = q0.w;
            r[rr][4] = q1.x; r[rr][5] = q1.y; r[rr][6] = q1.z; r[rr][7] = q1.w;
            r[rr][8] = q2.x; r[rr][9] = q2.y; r[rr][10] = q2.z; r[rr][11] = q2.w;
            r[rr][12] = p4[12];
          }
#pragma unroll
          for (int px = 0; px < 5; px++)
#pragma unroll
            for (int dy = 0; dy < 2; dy++)
#pragma unroll
              for (int dx = 0; dx < 2; dx++) {
                float s = acc[px][dy * 2 + dx];
                int x0 = 2 * px + dx;
#pragma unroll
                for (int ky = 0; ky < 3; ky++)
#pragma unroll
                  for (int kx = 0; kx < 3; kx++)
                    s += r[dy + ky][x0 + kx] * wvu[ky * 3 + kx];
                acc[px][dy * 2 + dx] = s;
              }
        }
      }
      { // icl = 24 (single)
        int icg = half * 25 + 24;
        float wv0[9];
#pragma unroll
        for (int i = 0; i < 9; i++) wv0[i] = wb[icg * 9 + i];
        float r[4][13];
        const float* rp = sh + 24 * 260 + 2 * py * 20;
#pragma unroll
        for (int rr = 0; rr < 4; rr++) {
          const float* p4 = rp + rr * 20;
          float4 q0 = *(const float4*)(p4);
          float4 q1 = *(const float4*)(p4 + 4);
          float4 q2 = *(const float4*)(p4 + 8);
          r[rr][0] = q0.x; r[rr][1] = q0.y; r[rr][2] = q0.z; r[rr][3] = q0.w;
          r[rr][4] = q1.x; r[rr][5] = q1.y; r[rr][6] = q1.z; r[rr][7] = q1.w;
          r[rr][8] = q2.x; r[rr][9] = q2.y; r[rr][10] = q2.z; r[rr][11] = q2.w;
          r[rr][12] = p4[12];
        }
#pragma unroll
        for (int px = 0; px < 5; px++)
#pragma unroll
          for (int dy = 0; dy < 2; dy++)
#pragma unroll
            for (int dx = 0; dx < 2; dx++) {
              float s = acc[px][dy * 2 + dx];
              int x0 = 2 * px + dx;
#pragma unroll
              for (int ky = 0; ky < 3; ky++)
#pragma unroll
                for (int kx = 0; kx < 3; kx++)
                  s += r[dy + ky][x0 + kx] * wv0[ky * 3 + kx];
              acc[px][dy * 2 + dx] = s;
            }
      }
    }
  }
  if (t >= 250) return;
  float bs = (mode ? c3b : c2b)[oc];
  float* outp = mode ? c3d : h2;
#pragma unroll
  for (int px = 0; px < 5; px++) {
    float m = fmaxf(fmaxf(acc[px][0], acc[px][1]), fmaxf(acc[px][2], acc[px][3]));
    outp[(b * 50 + oc) * 25 + py * 5 + px] = fmaxf(m + bs, 0.f);
  }
}

// ---------------- fused: router 2 + c32 (d2==0) + l12 (d2==1), h2 staged once ----------------
__global__ __launch_bounds__(256) void k_d2c(const float* __restrict__ h2,
                                             const float* __restrict__ d2w,
                                             const float* __restrict__ d2b,
                                             const float* __restrict__ c3w,
                                             const float* __restrict__ c3b,
                                             const float* __restrict__ c2l1w,
                                             const float* __restrict__ c2l1b,
                                             const int* __restrict__ d1i,
                                             int* __restrict__ d2i,
                                             float* __restrict__ outd2,
                                             float* __restrict__ c32,
                                             float* __restrict__ l12) {
  int b = blockIdx.x, t = threadIdx.x;
  __shared__ float hs[1250];
  __shared__ float wls[2500];
  __shared__ float bls[500];
  __shared__ float red[4][2];
  __shared__ int sd2;
  for (int i = t; i < 1250; i += 256) hs[i] = h2[b * 1250 + i];
  __syncthreads();
  float s0 = 0.f, s1 = 0.f;
  for (int i = t; i < 1250; i += 256) {
    float v = hs[i];
    s0 += v * d2w[i];
    s1 += v * d2w[1250 + i];
  }
#pragma unroll
  for (int off = 32; off >= 1; off >>= 1) {
    s0 += __shfl_down(s0, off);
    s1 += __shfl_down(s1, off);
  }
  if ((t & 63) == 0) { red[t >> 6][0] = s0; red[t >> 6][1] = s1; }
  __syncthreads();
  if (t == 0) {
    float l0 = d2b[0] + red[0][0] + red[1][0] + red[2][0] + red[3][0];
    float l1v = d2b[1] + red[0][1] + red[1][1] + red[2][1] + red[3][1];
    int idx = (l1v > l0) ? 1 : 0;
    d2i[b] = idx;
    outd2[b] = (float)idx;
    sd2 = idx;
  }
  __syncthreads();
  int d2v = sd2;
  if (d1i[b] != 0) return;
  if (d2v == 0) {
    if (t < 50) {
      const float* wb = c3w + t * 450;
      float a[4] = {0.f, 0.f, 0.f, 0.f};
      for (int ic = 0; ic < 50; ic++) {
        float r[4][4];
#pragma unroll
        for (int y = 0; y < 4; y++)
#pragma unroll
          for (int xx = 0; xx < 4; xx++) r[y][xx] = hs[ic * 25 + y * 5 + xx];
        float wv[9];
#pragma unroll
        for (int i = 0; i < 9; i++) wv[i] = wb[ic * 9 + i];
#pragma unroll
        for (int py = 0; py < 2; py++)
#pragma unroll
          for (int px = 0; px < 2; px++) {
            float s = a[py * 2 + px];
#pragma unroll
            for (int ky = 0; ky < 3; ky++)
#pragma unroll
              for (int kx = 0; kx < 3; kx++)
                s += r[py + ky][px + kx] * wv[ky * 3 + kx];
            a[py * 2 + px] = s;
          }
      }
      float m = fmaxf(fmaxf(a[0], a[1]), fmaxf(a[2], a[3]));
      c32[b * 50 + t] = fmaxf(m + c3b[t], 0.f);
    }
  } else {
    for (int i = t; i < 2500; i += 256) wls[i] = c2l1w[i];
    for (int i = t; i < 500; i += 256) bls[i] = c2l1b[i];
    __syncthreads();
    for (int o = t; o < 8300; o += 256) {
      int c = o / 166, tt = o % 166;
      const float* hb = hs + c * 25;
      float m = -INFINITY;
#pragma unroll
      for (int i = 0; i < 3; i++) {
        float a0 = hb[i * 5 + 0], a1 = hb[i * 5 + 1], a2 = hb[i * 5 + 2],
              a3 = hb[i * 5 + 3], a4 = hb[i * 5 + 4];
#pragma unroll
        for (int dj = 0; dj < 3; dj++) {
          int j = 3 * tt + dj;
          const float* wj = wls + j * 5;
          float s = bls[j] + a0 * wj[0] + a1 * wj[1] + a2 * wj[2] + a3 * wj[3] + a4 * wj[4];
          m = fmaxf(m, s);
        }
      }
      l12[b * 8300 + o] = m;
    }
  }
}

// ---------------- count active head rows per sample + prefix sum ----------------
__global__ void k_count(const int* __restrict__ d1i, const int* __restrict__ d2i,
                        int* __restrict__ off, int* __restrict__ ntot) {
  __shared__ int s[512];
  int t = threadIdx.x;
  int d1 = d1i[t], d2 = d2i[t];
  int nr = (d1 == 2) ? 500 : (d1 == 1) ? 25 : (d2 == 1) ? 166 : 1;
  s[t] = nr;
  __syncthreads();
  for (int o = 1; o < 512; o <<= 1) {
    int v = (t >= o) ? s[t - o] : 0;
    __syncthreads();
    s[t] += v;
    __syncthreads();
  }
  off[t] = s[t] - nr;
  if (t == 511) ntot[0] = s[511];
}

// ---------------- fill compacted row table: rowtab[i] = (b<<10) | out-row ----------------
__global__ void k_fill(const int* __restrict__ d1i, const int* __restrict__ d2i,
                       const int* __restrict__ off, int* __restrict__ rowtab) {
  int b = blockIdx.x;
  int d1 = d1i[b], d2 = d2i[b];
  int nr, rstart;
  if (d1 == 2)      { nr = 500; rstart = 0; }
  else if (d1 == 1) { nr = 25;  rstart = 667; }
  else if (d2 == 1) { nr = 166; rstart = 500; }
  else              { nr = 1;   rstart = 666; }
  int o = off[b];
  for (int i = threadIdx.x; i < nr; i += 256)
    rowtab[o + i] = (b << 10) | (rstart + i);
}

// XOR swizzle for the W1 LDS chunk (16KB): both write and read sides.
__device__ __forceinline__ int swz(int byteoff) {
  return byteoff ^ (((byteoff >> 7) & 7) << 4);
}

// ---------------- head GEMM, compacted (v8): zero global loads in the main loop ----------------
__global__ __launch_bounds__(256, 3) void k_headc(
    const float* __restrict__ c3d, const float* __restrict__ c32,
    const float* __restrict__ p7, const float* __restrict__ l12buf,
    const int* __restrict__ rowtab, const int* __restrict__ ntotp,
    const __bf16* __restrict__ W1p, const float* __restrict__ W2t,
    const float* __restrict__ l2b,
    const float* __restrict__ c1l1w, const float* __restrict__ c1l1b,
    float* __restrict__ out) {
  int ntot = ntotp[0];
  int blkbase = blockIdx.x * 64;
  if (blkbase >= ntot) return;          // uniform whole-block exit (before any barrier)

  __shared__ __align__(16) char wlds[16384];    // W1 phase buffer (8 j-tiles)
  __shared__ __align__(16) float w2s[512 * 12]; // W2, staged once (24KB)
  int t = threadIdx.x;
  int wv = t >> 6, lane = t & 63;
  int lr = lane & 15, lg = lane >> 4;

  // stage W2 once (1536 float4s / 256 threads = 6 each, coalesced)
  for (int i = t; i < 1536; i += 256)
    ((float4*)w2s)[i] = ((const float4*)W2t)[i];

  // ---- gather this lane's A-frag row (A layout: row = lr)
  int row = blkbase + wv * 16 + lr;
  int rowc = (row < ntot) ? row : (ntot - 1);
  int e = rowtab[rowc];
  int gb = e >> 10, orow = e & 1023;
  bf16x8 a1[2];
  {
    float pv = 0.f;
    const float* wsrc = nullptr;
    const float* bsrc = nullptr;
    const float* src = nullptr;
    bool isl11 = (orow < 500);
    if (isl11) {
      pv = p7[gb * 50 + orow / 10];
      int q = (orow % 10) * 50;
      wsrc = c1l1w + q;
      bsrc = c1l1b + q;
    } else if (orow < 666) {
      src = l12buf + gb * 8300 + (orow - 500) * 50;
    } else if (orow == 666) {
      src = c32 + gb * 50;
    } else {
      src = c3d + gb * 1250 + (orow - 667) * 50;
    }
#pragma unroll
    for (int ks = 0; ks < 2; ++ks) {
      float v[8];
      int k0 = ks * 32 + lg * 8;
      if (ks == 0 || lg < 2) {
        if (isl11) {
#pragma unroll
          for (int i = 0; i < 8; i += 2) {
            float2 wq = *(const float2*)(wsrc + k0 + i);
            float2 bq = *(const float2*)(bsrc + k0 + i);
            v[i] = pv * wq.x + bq.x;
            v[i + 1] = pv * wq.y + bq.y;
          }
        } else {
#pragma unroll
          for (int i = 0; i < 8; i += 2) {
            float2 q = *(const float2*)(src + k0 + i);
            v[i] = q.x; v[i + 1] = q.y;
          }
        }
      } else if (lg == 2) {
        float2 q;
        if (isl11) {
          float2 wq = *(const float2*)(wsrc + 48);
          float2 bq = *(const float2*)(bsrc + 48);
          q.x = pv * wq.x + bq.x; q.y = pv * wq.y + bq.y;
        } else {
          q = *(const float2*)(src + 48);
        }
        v[0] = q.x; v[1] = q.y; v[2] = 1.0f;
        v[3] = 0.f; v[4] = 0.f; v[5] = 0.f; v[6] = 0.f; v[7] = 0.f;
      } else {
#pragma unroll
        for (int i = 0; i < 8; ++i) v[i] = 0.f;
      }
      bf16x8 a;
#pragma unroll
      for (int i = 0; i < 8; ++i) a[i] = (__bf16)v[i];
      a1[ks] = a;
    }
  }

  float acc[4][10];
#pragma unroll
  for (int r = 0; r < 4; ++r)
#pragma unroll
    for (int n = 0; n < 10; ++n) acc[r][n] = 0.f;

  for (int p = 0; p < 4; ++p) {
    if (p > 0) __syncthreads();         // all waves done reading phase p-1
    // stage 16KB of W1 (j-tiles p*8 .. p*8+7), swizzled (64B/thread)
    {
      const char* src = (const char*)W1p + p * 16384 + t * 64;
#pragma unroll
      for (int i = 0; i < 4; ++i) {
        float4 q = *(const float4*)(src + i * 16);
        *(float4*)(wlds + swz(t * 64 + i * 16)) = q;
      }
    }
    __syncthreads();
#pragma unroll
    for (int jl = 0; jl < 8; ++jl) {
      int jt = p * 8 + jl;
      int boff = jl * 2048 + lr * 128 + lg * 16;
      bf16x8 b0 = *(const bf16x8*)(wlds + swz(boff));
      bf16x8 b1 = *(const bf16x8*)(wlds + swz(boff + 64));
      const float* wr = w2s + (jt * 16 + lr) * 12;
      float4 w20 = *(const float4*)(wr);
      float4 w21 = *(const float4*)(wr + 4);
      float2 w22 = *(const float2*)(wr + 8);
      f32x4 h = {0.f, 0.f, 0.f, 0.f};
      h = __builtin_amdgcn_mfma_f32_16x16x32_bf16(a1[0], b0, h, 0, 0, 0);
      h = __builtin_amdgcn_mfma_f32_16x16x32_bf16(a1[1], b1, h, 0, 0, 0);
      float w2v[10] = {w20.x, w20.y, w20.z, w20.w, w21.x, w21.y, w21.z, w21.w, w22.x, w22.y};
#pragma unroll
      for (int r = 0; r < 4; ++r) {
        float hv = fmaxf(h[r], 0.f);
#pragma unroll
        for (int n = 0; n < 10; ++n) acc[r][n] += hv * w2v[n];
      }
    }
  }

  // ---- reduce over 16 lr lanes (j-partition)
#pragma unroll
  for (int r = 0; r < 4; ++r)
#pragma unroll
    for (int n = 0; n < 10; ++n) {
      float v = acc[r][n];
      v += __shfl_xor(v, 1);
      v += __shfl_xor(v, 2);
      v += __shfl_xor(v, 4);
      v += __shfl_xor(v, 8);
      acc[r][n] = v;
    }
  // ---- in-lane log-softmax + write (lane lr==0 holds rows m = lg*4 + r)
  if (lr == 0) {
#pragma unroll
    for (int r = 0; r < 4; ++r) {
      int rw = blkbase + wv * 16 + lg * 4 + r;
      if (rw < ntot) {
        int e2 = rowtab[rw];
        int b2 = e2 >> 10, orow2 = e2 & 1023;
        float o[10];
        float m = -INFINITY;
#pragma unroll
        for (int n = 0; n < 10; ++n) {
          o[n] = acc[r][n] + l2b[n];
          m = fmaxf(m, o[n]);
        }
        float s = 0.f;
#pragma unroll
        for (int n = 0; n < 10; ++n) s += expf(o[n] - m);
        float lse = m + logf(s);
        float* orowp = out + (b2 * 692 + orow2) * 10;
#pragma unroll
        for (int n = 0; n < 10; ++n) orowp[n] = o[n] - lse;
      }
    }
  }
}

extern "C" void kernel_launch(void* const* d_in, const int* in_sizes, int n_in,
                              void* d_out, int out_size, void* d_ws, size_t ws_size,
                              hipStream_t stream) {
  const float* x     = (const float*)d_in[0];
  const float* c1w   = (const float*)d_in[1];
  const float* c1b   = (const float*)d_in[2];
  const float* c2w   = (const float*)d_in[3];
  const float* c2b   = (const float*)d_in[4];
  const float* c3w   = (const float*)d_in[5];
  const float* c3b   = (const float*)d_in[6];
  const float* l1w   = (const float*)d_in[7];
  const float* l1b   = (const float*)d_in[8];
  const float* l2w   = (const float*)d_in[9];
  const float* l2b   = (const float*)d_in[10];
  const float* d1w   = (const float*)d_in[11];
  const float* d1b   = (const float*)d_in[12];
  const float* d2w   = (const float*)d_in[13];
  const float* d2b   = (const float*)d_in[14];
  const float* c13w  = (const float*)d_in[15];
  const float* c13b  = (const float*)d_in[16];
  const float* c1l1w = (const float*)d_in[17];
  const float* c1l1b = (const float*)d_in[18];
  const float* c2l1w = (const float*)d_in[19];
  const float* c2l1b = (const float*)d_in[20];
  float* out = (float*)d_out;

  float* ws  = (float*)d_ws;
  float* h1  = ws;                 // 4,326,400 floats
  float* h2  = h1 + 4326400;       // 640,000
  float* c3d = h2 + 640000;        // 640,000
  float* c32 = c3d + 640000;       // 25,600
  float* p7  = c32 + 25600;        // 25,600
  int*   d1i = (int*)(p7 + 25600); // 512
  int*   d2i = d1i + 512;          // 512
  __bf16* W1p = (__bf16*)(d2i + 512);    // 512*64 bf16 = 16384 floats
  float* W2t = (float*)(W1p + 512 * 64); // 6144 floats
  int* off    = (int*)(W2t + 512 * 12);  // 512
  int* ntot   = off + 512;               // 4 (padded)
  int* rowtab = ntot + 4;                // 262,144
  // l12buf aliases h1: written by k_d2c AFTER the last h1 reader (k_conv5m).
  float* l12buf = h1;

  float* outd1 = out + 512 * 692 * 10;
  float* outd2 = outd1 + 512;

  k_zero<<<3460, 256, 0, stream>>>(out, 885510);
  k_pack<<<153, 256, 0, stream>>>(l1w, l1b, l2w, W1p, W2t);
  k_conv1<<<16900, 256, 0, stream>>>(x, c1w, c1b, h1);
  k_d1p7<<<512, 256, 0, stream>>>(h1, d1w, d1b, d1i, outd1, p7);
  k_conv5m<<<1024, 256, 0, stream>>>(h1, c2w, c2b, c3w, c3b, d1i,
                                     c13w, c13b, h2, c3d);
  k_d2c<<<512, 256, 0, stream>>>(h2, d2w, d2b, c3w, c3b, c2l1w, c2l1b,
                                 d1i, d2i, outd2, c32, l12buf);
  k_count<<<1, 512, 0, stream>>>(d1i, d2i, off, ntot);
  k_fill<<<512, 256, 0, stream>>>(d1i, d2i, off, rowtab);
  k_headc<<<4000, 256, 0, stream>>>(c3d, c32, p7, l12buf, rowtab, ntot,
                                    W1p, W2t, l2b, c1l1w, c1l1b, out);
}